// Round 3
// baseline (1184.650 us; speedup 1.0000x reference)
//
#include <hip/hip_runtime.h>

#define NN 100000
#define NE 1200000
#define NG 2048
#define D 64
#define C 2

#define SCAN_T 1024
#define CHUNK ((NN + SCAN_T - 1) / SCAN_T)   // 98

__device__ __forceinline__ int atomAddI(int* p, int v) {
    return __hip_atomic_fetch_add(p, v, __ATOMIC_RELAXED, __HIP_MEMORY_SCOPE_AGENT);
}

// deg[dst[e]]++
__global__ void k_hist(const int* __restrict__ dst, int* __restrict__ deg) {
    int e = blockIdx.x * blockDim.x + threadIdx.x;
    if (e < NE) atomAddI(&deg[dst[e]], 1);
}

// single-block exclusive scan: deg[NN] -> start[NN+1]; cursor = copy of start
__global__ void k_scan(const int* __restrict__ deg, int* __restrict__ start,
                       int* __restrict__ cursor) {
    __shared__ int sums[SCAN_T];
    int t = threadIdx.x;
    int lo = t * CHUNK, hi = min(lo + CHUNK, NN);
    int s = 0;
    for (int i = lo; i < hi; ++i) s += deg[i];
    sums[t] = s;
    __syncthreads();
    for (int off = 1; off < SCAN_T; off <<= 1) {
        int v = (t >= off) ? sums[t - off] : 0;
        __syncthreads();
        sums[t] += v;
        __syncthreads();
    }
    int run = sums[t] - s;  // exclusive prefix of this chunk
    for (int i = lo; i < hi; ++i) {
        start[i] = run; cursor[i] = run;
        run += deg[i];
    }
    if (t == 0) start[NN] = NE;
}

// csr_src[cursor[dst[e]]++] = src[e]
__global__ void k_build(const int* __restrict__ src, const int* __restrict__ dst,
                        int* __restrict__ cursor, int* __restrict__ csr_src) {
    int e = blockIdx.x * blockDim.x + threadIdx.x;
    if (e < NE) {
        int pos = atomAddI(&cursor[dst[e]], 1);
        csr_src[pos] = src[e];
    }
}

// h0[n, :] = emb[x[n], :]
__global__ void k_embed(const int* __restrict__ x, const float4* __restrict__ emb,
                        float4* __restrict__ h) {
    int tid = blockIdx.x * blockDim.x + threadIdx.x;
    if (tid >= NN * 16) return;
    int n = tid >> 4;
    int c = tid & 15;
    h[tid] = emb[x[n] * 16 + c];
}

// Fused mean-aggregate (CSR gather) + SAGE linear + ReLU.
// One wave per node at a time; lane d = output feature d; Wl/Wr row d lives in
// the lane's registers (amortized over NPW nodes). Gather: for each incoming
// edge, src id broadcast via __shfl, then a coalesced 256B row read of hin.
#define NPW 25   // block = 4 waves covers 100 nodes; grid = 1000
__global__ void k_sage(const int* __restrict__ start, const int* __restrict__ csr_src,
                       const float* __restrict__ hin,
                       const float4* __restrict__ Wl, const float* __restrict__ bl,
                       const float4* __restrict__ Wr, float* __restrict__ hout) {
    __shared__ __align__(16) float lds_a[4][D];
    __shared__ __align__(16) float lds_h[4][D];
    int lane = threadIdx.x & 63;
    int wave = threadIdx.x >> 6;

    float4 wl[16], wr[16];
#pragma unroll
    for (int i = 0; i < 16; ++i) {
        wl[i] = Wl[lane * 16 + i];
        wr[i] = Wr[lane * 16 + i];
    }
    float bias = bl[lane];

    int n0 = blockIdx.x * (4 * NPW) + wave * NPW;
    for (int j = 0; j < NPW; ++j) {
        int n = __builtin_amdgcn_readfirstlane(n0 + j);
        int s0 = start[n], s1 = start[n + 1];
        float acc = 0.f;
        for (int i0 = s0; i0 < s1; i0 += 64) {
            int idx = i0 + lane;
            int sid = (idx < s1) ? csr_src[idx] : 0;
            int m = s1 - i0; if (m > 64) m = 64;
#pragma unroll 4
            for (int jj = 0; jj < m; ++jj) {
                int sn = __shfl(sid, jj, 64);
                acc += hin[(size_t)sn * D + lane];
            }
        }
        float inv = 1.0f / (float)max(s1 - s0, 1);
        lds_a[wave][lane] = acc * inv;          // pre-scale (linear, equivalent)
        lds_h[wave][lane] = hin[(size_t)n * D + lane];
        // same-wave LDS RAW: in-order wave + compiler lgkmcnt; no barrier needed
        const float4* a4p = (const float4*)lds_a[wave];
        const float4* h4p = (const float4*)lds_h[wave];
        float a = 0.f, r = 0.f;
#pragma unroll
        for (int k = 0; k < 16; ++k) {
            float4 a4 = a4p[k], h4 = h4p[k];
            a += a4.x * wl[k].x + a4.y * wl[k].y + a4.z * wl[k].z + a4.w * wl[k].w;
            r += h4.x * wr[k].x + h4.y * wr[k].y + h4.z * wr[k].z + h4.w * wr[k].w;
        }
        hout[(size_t)n * D + lane] = fmaxf(a + bias + r, 0.f);
    }
}

// batch is sorted: graph g occupies nodes [gs[g], gs[g+1])
__global__ void k_bounds(const int* __restrict__ batch, int* __restrict__ gs) {
    int n = blockIdx.x * blockDim.x + threadIdx.x;
    if (n >= NN) return;
    int b = batch[n];
    if (n == 0) {
        for (int g = 0; g <= b; ++g) gs[g] = 0;
    } else {
        int bp = batch[n - 1];
        for (int g = bp + 1; g <= b; ++g) gs[g] = n;
    }
    if (n == NN - 1) {
        for (int g = b + 1; g <= NG; ++g) gs[g] = NN;
    }
}

// fused mean-pool + output linear; one wave per graph
__global__ void k_pool(const int* __restrict__ gs, const float* __restrict__ h,
                       const float* __restrict__ Wout, const float* __restrict__ bout,
                       float* __restrict__ out) {
    int lane = threadIdx.x & 63;
    int wave = threadIdx.x >> 6;
    int g = blockIdx.x * 4 + wave;        // NG = 2048, grid = 512
    int s0 = gs[g], s1 = gs[g + 1];
    float p = 0.f;
    for (int n = s0; n < s1; ++n) p += h[(size_t)n * D + lane];
    p *= 1.0f / (float)max(s1 - s0, 1);
    float c0 = p * Wout[lane];
    float c1 = p * Wout[D + lane];
#pragma unroll
    for (int off = 32; off > 0; off >>= 1) {
        c0 += __shfl_down(c0, off, 64);
        c1 += __shfl_down(c1, off, 64);
    }
    if (lane == 0) {
        out[g * C + 0] = c0 + bout[0];
        out[g * C + 1] = c1 + bout[1];
    }
}

extern "C" void kernel_launch(void* const* d_in, const int* in_sizes, int n_in,
                              void* d_out, int out_size, void* d_ws, size_t ws_size,
                              hipStream_t stream) {
    const int*   x     = (const int*)d_in[0];
    const int*   src   = (const int*)d_in[1];          // edge_index[0]
    const int*   dst   = src + NE;                     // edge_index[1]
    const int*   batch = (const int*)d_in[2];
    const float* emb   = (const float*)d_in[3];
    const float* W1l   = (const float*)d_in[4];
    const float* b1l   = (const float*)d_in[5];
    const float* W1r   = (const float*)d_in[6];
    const float* W2l   = (const float*)d_in[7];
    const float* b2l   = (const float*)d_in[8];
    const float* W2r   = (const float*)d_in[9];
    const float* Wout  = (const float*)d_in[10];
    const float* bout  = (const float*)d_in[11];
    float* out = (float*)d_out;

    // ws layout: h0, h1 first (16B-aligned at base), then int arrays
    float* h0    = (float*)d_ws;                    // NN*D
    float* h1    = h0 + (size_t)NN * D;             // NN*D
    int* deg     = (int*)(h1 + (size_t)NN * D);     // NN
    int* startA  = deg + NN;                        // NN+1
    int* cursor  = startA + NN + 1;                 // NN
    int* csr     = cursor + NN;                     // NE
    int* gs      = csr + NE;                        // NG+1

    hipMemsetAsync(deg, 0, NN * sizeof(int), stream);

    // CSR build (shared by both layers)
    k_hist <<<(NE + 255) / 256, 256, 0, stream>>>(dst, deg);
    k_scan <<<1, SCAN_T, 0, stream>>>(deg, startA, cursor);
    k_build<<<(NE + 255) / 256, 256, 0, stream>>>(src, dst, cursor, csr);

    k_embed<<<(NN * 16 + 255) / 256, 256, 0, stream>>>(x, (const float4*)emb, (float4*)h0);
    k_bounds<<<(NN + 255) / 256, 256, 0, stream>>>(batch, gs);

    // ---- layer 1 ----
    k_sage<<<NN / (4 * NPW), 256, 0, stream>>>(startA, csr, h0, (const float4*)W1l, b1l,
                                               (const float4*)W1r, h1);
    // ---- layer 2 ----
    k_sage<<<NN / (4 * NPW), 256, 0, stream>>>(startA, csr, h1, (const float4*)W2l, b2l,
                                               (const float4*)W2r, h0);

    // ---- readout ----
    k_pool<<<NG / 4, 256, 0, stream>>>(gs, h0, Wout, bout, out);
}

// Round 4
// 872.737 us; speedup vs baseline: 1.3574x; 1.3574x over previous
//
#include <hip/hip_runtime.h>

#define NN 100000
#define NE 1200000
#define NG 2048
#define D 64
#define C 2

#define SB 512
#define NB ((NN + SB - 1) / SB)   // 196 scan blocks

__device__ __forceinline__ int atomAddI(int* p, int v) {
    return __hip_atomic_fetch_add(p, v, __ATOMIC_RELAXED, __HIP_MEMORY_SCOPE_AGENT);
}

// ---------------- CSR build ----------------
__global__ void k_hist(const int* __restrict__ dst, int* __restrict__ deg) {
    int e = blockIdx.x * blockDim.x + threadIdx.x;
    if (e < NE) atomAddI(&deg[dst[e]], 1);
}

// per-block (512-elem) local exclusive scan, coalesced
__global__ void k_scan1(const int* __restrict__ deg, int* __restrict__ locx,
                        int* __restrict__ bsum) {
    __shared__ int sm[256];
    int t = threadIdx.x;
    int i0 = blockIdx.x * SB + 2 * t;
    int d0 = (i0 < NN) ? deg[i0] : 0;
    int d1 = (i0 + 1 < NN) ? deg[i0 + 1] : 0;
    int s = d0 + d1;
    sm[t] = s;
    __syncthreads();
    for (int off = 1; off < 256; off <<= 1) {
        int v = (t >= off) ? sm[t - off] : 0;
        __syncthreads();
        sm[t] += v;
        __syncthreads();
    }
    int ex = sm[t] - s;   // exclusive prefix over pairs
    if (i0 < NN) locx[i0] = ex;
    if (i0 + 1 < NN) locx[i0 + 1] = ex + d0;
    if (t == 255) bsum[blockIdx.x] = sm[255];
}

__global__ void k_scan2(const int* __restrict__ bsum, int* __restrict__ boff) {
    __shared__ int sm[NB];
    int t = threadIdx.x;
    if (t < NB) sm[t] = bsum[t];
    __syncthreads();
    if (t == 0) {
        int run = 0;
        for (int i = 0; i < NB; ++i) { int v = sm[i]; sm[i] = run; run += v; }
    }
    __syncthreads();
    if (t < NB) boff[t] = sm[t];
}

__global__ void k_scan3(const int* __restrict__ locx, const int* __restrict__ boff,
                        int* __restrict__ start, int* __restrict__ cursor) {
    int i = blockIdx.x * SB + threadIdx.x;
    if (i < NN) {
        int v = locx[i] + boff[blockIdx.x];
        start[i] = v;
        cursor[i] = v;
    }
    if (i == 0) start[NN] = NE;
}

__global__ void k_build(const int* __restrict__ src, const int* __restrict__ dst,
                        int* __restrict__ cursor, int* __restrict__ csr_src) {
    int e = blockIdx.x * blockDim.x + threadIdx.x;
    if (e < NE) {
        int pos = atomAddI(&cursor[dst[e]], 1);
        csr_src[pos] = src[e];
    }
}

// ---------------- embedding -> transposed slabs T0[c][n][8] ----------------
__global__ void k_embedT(const int* __restrict__ x, const float* __restrict__ emb,
                         float* __restrict__ T0) {
    int tid = blockIdx.x * blockDim.x + threadIdx.x;   // NN*64
    if (tid >= NN * 64) return;
    int c = tid / (NN * 8);
    int r = tid % (NN * 8);
    int n = r >> 3, f = r & 7;
    T0[tid] = emb[(size_t)x[n] * 64 + c * 8 + f];
}

// ---------------- chunked CSR aggregate ----------------
// grid (1000, 8): y = feature chunk. Per pass the 3.2 MB slab gT[c] is
// L2-resident. Wave layout: lane = e_sub*8 + f -> 8 edges x 8 features per
// load instruction; shfl_xor reduce over e_sub.
__global__ void k_agg8(const int* __restrict__ start, const int* __restrict__ csr,
                       const float* __restrict__ gT, float* __restrict__ aggT) {
    int lane = threadIdx.x & 63;
    int wave = threadIdx.x >> 6;
    int c = blockIdx.y;
    const float* gsl = gT + (size_t)c * NN * 8;
    float* asl = aggT + (size_t)c * NN * 8;
    int f = lane & 7;
    int es = lane >> 3;          // 0..7
    int n0 = blockIdx.x * 100 + wave * 25;
    for (int j = 0; j < 25; ++j) {
        int n = __builtin_amdgcn_readfirstlane(n0 + j);
        int s0 = start[n], s1 = start[n + 1];
        float acc = 0.f;
        for (int i0 = s0; i0 < s1; i0 += 8) {
            int e = i0 + es;
            if (e < s1) {
                int s = csr[e];
                acc += gsl[(size_t)s * 8 + f];
            }
        }
        acc += __shfl_xor(acc, 8, 64);
        acc += __shfl_xor(acc, 16, 64);
        acc += __shfl_xor(acc, 32, 64);
        if (lane < 8) asl[(size_t)n * 8 + lane] = acc;
    }
}

// ---------------- SAGE linear (+ReLU) from slabs ----------------
// lane d holds Wl/Wr row d in registers; node uniform per wave; agg/root read
// via wave-uniform loads from the slabs. Writes row-major and/or slab layout.
// outSlab may alias rootT (in-place): every root load precedes the store.
__global__ void k_lin(const int* __restrict__ start, const float* __restrict__ aggT,
                      const float* rootT,
                      const float4* __restrict__ Wl, const float* __restrict__ bl,
                      const float4* __restrict__ Wr,
                      float* outRow, float* outSlab) {
    int lane = threadIdx.x & 63;
    int wave = threadIdx.x >> 6;

    float4 wl[16], wr[16];
#pragma unroll
    for (int i = 0; i < 16; ++i) {
        wl[i] = Wl[lane * 16 + i];
        wr[i] = Wr[lane * 16 + i];
    }
    float bias = bl[lane];

    int n0 = blockIdx.x * 100 + wave * 25;
    for (int j = 0; j < 25; ++j) {
        int n = __builtin_amdgcn_readfirstlane(n0 + j);
        int s0 = start[n], s1 = start[n + 1];
        float inv = 1.0f / (float)max(s1 - s0, 1);
        float a = 0.f, r = 0.f;
#pragma unroll
        for (int c2 = 0; c2 < 8; ++c2) {
            const float4* ap = (const float4*)(aggT + (size_t)c2 * NN * 8 + (size_t)n * 8);
            const float4* rp = (const float4*)(rootT + (size_t)c2 * NN * 8 + (size_t)n * 8);
            float4 a0 = ap[0], a1 = ap[1];
            float4 r0 = rp[0], r1 = rp[1];
            float4 w0 = wl[2 * c2], w1 = wl[2 * c2 + 1];
            float4 u0 = wr[2 * c2], u1 = wr[2 * c2 + 1];
            a += a0.x * w0.x + a0.y * w0.y + a0.z * w0.z + a0.w * w0.w
               + a1.x * w1.x + a1.y * w1.y + a1.z * w1.z + a1.w * w1.w;
            r += r0.x * u0.x + r0.y * u0.y + r0.z * u0.z + r0.w * u0.w
               + r1.x * u1.x + r1.y * u1.y + r1.z * u1.z + r1.w * u1.w;
        }
        float v = fmaxf(a * inv + bias + r, 0.f);
        if (outRow)  outRow[(size_t)n * D + lane] = v;
        if (outSlab) outSlab[(size_t)(lane >> 3) * NN * 8 + (size_t)n * 8 + (lane & 7)] = v;
    }
}

// ---------------- readout ----------------
__global__ void k_bounds(const int* __restrict__ batch, int* __restrict__ gs) {
    int n = blockIdx.x * blockDim.x + threadIdx.x;
    if (n >= NN) return;
    int b = batch[n];
    if (n == 0) {
        for (int g = 0; g <= b; ++g) gs[g] = 0;
    } else {
        int bp = batch[n - 1];
        for (int g = bp + 1; g <= b; ++g) gs[g] = n;
    }
    if (n == NN - 1) {
        for (int g = b + 1; g <= NG; ++g) gs[g] = NN;
    }
}

__global__ void k_pool(const int* __restrict__ gs, const float* __restrict__ h,
                       const float* __restrict__ Wout, const float* __restrict__ bout,
                       float* __restrict__ out) {
    int lane = threadIdx.x & 63;
    int wave = threadIdx.x >> 6;
    int g = blockIdx.x * 4 + wave;
    int s0 = gs[g], s1 = gs[g + 1];
    float p = 0.f;
    for (int n = s0; n < s1; ++n) p += h[(size_t)n * D + lane];
    p *= 1.0f / (float)max(s1 - s0, 1);
    float c0 = p * Wout[lane];
    float c1 = p * Wout[D + lane];
#pragma unroll
    for (int off = 32; off > 0; off >>= 1) {
        c0 += __shfl_down(c0, off, 64);
        c1 += __shfl_down(c1, off, 64);
    }
    if (lane == 0) {
        out[g * C + 0] = c0 + bout[0];
        out[g * C + 1] = c1 + bout[1];
    }
}

extern "C" void kernel_launch(void* const* d_in, const int* in_sizes, int n_in,
                              void* d_out, int out_size, void* d_ws, size_t ws_size,
                              hipStream_t stream) {
    const int*   x     = (const int*)d_in[0];
    const int*   src   = (const int*)d_in[1];
    const int*   dst   = src + NE;
    const int*   batch = (const int*)d_in[2];
    const float* emb   = (const float*)d_in[3];
    const float* W1l   = (const float*)d_in[4];
    const float* b1l   = (const float*)d_in[5];
    const float* W1r   = (const float*)d_in[6];
    const float* W2l   = (const float*)d_in[7];
    const float* b2l   = (const float*)d_in[8];
    const float* W2r   = (const float*)d_in[9];
    const float* Wout  = (const float*)d_in[10];
    const float* bout  = (const float*)d_in[11];
    float* out = (float*)d_out;

    float* T0 = (float*)d_ws;                 // NN*64 (slabs, gather src/root)
    float* TA = T0 + (size_t)NN * 64;         // NN*64 (agg slabs)
    float* h2 = TA + (size_t)NN * 64;         // NN*64 (row-major, for pool)
    int* deg    = (int*)(h2 + (size_t)NN * 64);  // NN
    int* startA = deg + NN;                      // NN+1
    int* cursor = startA + NN + 1;               // NN
    int* locx   = cursor + NN;                   // NN
    int* bsum   = locx + NN;                     // NB
    int* boff   = bsum + NB;                     // NB
    int* gs     = boff + NB;                     // NG+1
    int* csr    = gs + NG + 1;                   // NE

    hipMemsetAsync(deg, 0, NN * sizeof(int), stream);

    k_hist <<<(NE + 255) / 256, 256, 0, stream>>>(dst, deg);
    k_scan1<<<NB, 256, 0, stream>>>(deg, locx, bsum);
    k_scan2<<<1, 256, 0, stream>>>(bsum, boff);
    k_scan3<<<NB, SB, 0, stream>>>(locx, boff, startA, cursor);
    k_build<<<(NE + 255) / 256, 256, 0, stream>>>(src, dst, cursor, csr);

    k_embedT<<<(NN * 64 + 255) / 256, 256, 0, stream>>>(x, emb, T0);
    k_bounds<<<(NN + 255) / 256, 256, 0, stream>>>(batch, gs);

    // ---- layer 1 ----
    k_agg8<<<dim3(1000, 8), 256, 0, stream>>>(startA, csr, T0, TA);
    k_lin <<<1000, 256, 0, stream>>>(startA, TA, T0, (const float4*)W1l, b1l,
                                     (const float4*)W1r, nullptr, T0);  // h1 slabs in place
    // ---- layer 2 ----
    k_agg8<<<dim3(1000, 8), 256, 0, stream>>>(startA, csr, T0, TA);
    k_lin <<<1000, 256, 0, stream>>>(startA, TA, T0, (const float4*)W2l, b2l,
                                     (const float4*)W2r, h2, nullptr);

    // ---- readout ----
    k_pool<<<NG / 4, 256, 0, stream>>>(gs, h2, Wout, bout, out);
}